// Round 1
// baseline (367.513 us; speedup 1.0000x reference)
//
#include <hip/hip_runtime.h>

// RRSVM rank-weighted pooling, 3x3 / stride 2 / pad 1.
// x: [B=32, C=64, H=112, W=112] fp32;  s: [C, 3, 3] fp32
// out0: [B,C,56,56] fp32 ; out1: order [B,C,56,56,9] written as fp32
// (harness reads whole d_out as one fp32 stream and splits per-output).

constexpr int B  = 32;
constexpr int C  = 64;
constexpr int H  = 112;
constexpr int W  = 112;
constexpr int HO = 56;
constexpr int WO = 56;
constexpr int KK = 9;
constexpr int NPIX = HO * WO;          // 3136 windows per (b,c) plane

__global__ __launch_bounds__(256) void rrsvm_kernel(
    const float* __restrict__ x, const float* __restrict__ s,
    float* __restrict__ out, float* __restrict__ order)
{
    const int plane = blockIdx.y;                     // b*C + c  (block-uniform)
    const int pix   = blockIdx.x * 256 + threadIdx.x; // window id in plane
    if (pix >= NPIX) return;
    const int ho = pix / WO;
    const int wo = pix - ho * WO;
    const int c  = plane & (C - 1);                   // C = 64, power of 2

    const float* xp = x + (size_t)plane * (H * W);

    float v[KK];
    int   id[KK];
    const int iy0 = 2 * ho - 1;
    const int ix0 = 2 * wo - 1;
#pragma unroll
    for (int dy = 0; dy < 3; ++dy) {
        const int  iy  = iy0 + dy;
        const bool yok = ((unsigned)iy < (unsigned)H);
#pragma unroll
        for (int dx = 0; dx < 3; ++dx) {
            const int  ix = ix0 + dx;
            const int  k  = dy * 3 + dx;
            const bool ok = yok && ((unsigned)ix < (unsigned)W);
            v[k]  = ok ? xp[iy * W + ix] : 0.0f;
            id[k] = k;
        }
    }

    // Compare-exchange: position a keeps the element that comes FIRST in the
    // stable descending order (greater value; on exact tie, smaller index).
    // This is a strict total order, so the network reproduces jnp's stable
    // argsort(-patches) exactly (ties only occur among padded zeros).
    auto CE = [&](int a, int b) {
        const float va = v[a],  vb = v[b];
        const int   ia = id[a], ib = id[b];
        const bool sw = (va < vb) || ((va == vb) && (ia > ib));
        v[a]  = sw ? vb : va;  v[b]  = sw ? va : vb;
        id[a] = sw ? ib : ia;  id[b] = sw ? ia : ib;
    };

    // Batcher odd-even mergesort on elements 0..7 (19 CEs) ...
    CE(0,1); CE(2,3); CE(4,5); CE(6,7);
    CE(0,2); CE(1,3); CE(4,6); CE(5,7);
    CE(1,2); CE(5,6);
    CE(0,4); CE(1,5); CE(2,6); CE(3,7);
    CE(2,4); CE(3,5);
    CE(1,2); CE(3,4); CE(5,6);
    // ... then insert element 8 via an exchange chain (8 CEs). Total 27.
    CE(7,8); CE(6,7); CE(5,6); CE(4,5); CE(3,4); CE(2,3); CE(1,2); CE(0,1);

    // Weighted sum with per-channel rank weights. c is block-uniform ->
    // these become scalar (s_load) reads.
    const float* sc = s + c * KK;
    float acc = 0.0f;
#pragma unroll
    for (int k = 0; k < KK; ++k) acc = fmaf(v[k], sc[k], acc);

    const size_t win = (size_t)plane * NPIX + pix;
    out[win] = acc;

    float* ob = order + win * (size_t)KK;
#pragma unroll
    for (int k = 0; k < KK; ++k) ob[k] = (float)id[k];
}

extern "C" void kernel_launch(void* const* d_in, const int* in_sizes, int n_in,
                              void* d_out, int out_size, void* d_ws, size_t ws_size,
                              hipStream_t stream) {
    const float* x = (const float*)d_in[0];
    const float* s = (const float*)d_in[1];
    float* out   = (float*)d_out;
    float* order = out + (size_t)B * C * NPIX;   // second output, flat after first

    dim3 grid((NPIX + 255) / 256, B * C);        // (13, 2048)
    rrsvm_kernel<<<grid, dim3(256), 0, stream>>>(x, s, out, order);
}

// Round 2
// 327.986 us; speedup vs baseline: 1.1205x; 1.1205x over previous
//
#include <hip/hip_runtime.h>

// RRSVM rank-weighted pooling, 3x3 / stride 2 / pad 1.
// x: [B=32, C=64, H=112, W=112] fp32;  s: [C, 3, 3] fp32
// out0: [B,C,56,56] fp32 ; out1: order [B,C,56,56,9] written as fp32.
//
// R2: order writes staged through LDS -> coalesced float4 writeback.
// (R1 was 367us vs ~57us floor: 9-way scattered order stores, 36B lane
// stride, ~9x write-transaction cost on the 231MB order array.)

constexpr int B  = 32;
constexpr int C  = 64;
constexpr int H  = 112;
constexpr int W  = 112;
constexpr int HO = 56;
constexpr int WO = 56;
constexpr int KK = 9;
constexpr int NPIX = HO * WO;          // 3136 windows per (b,c) plane
constexpr int BLK  = 256;

__global__ __launch_bounds__(BLK) void rrsvm_kernel(
    const float* __restrict__ x, const float* __restrict__ s,
    float* __restrict__ out, float* __restrict__ order)
{
    __shared__ float lorder[BLK * KK];            // 9216 B

    const int plane = blockIdx.y;                 // b*C + c  (block-uniform)
    const int tid   = threadIdx.x;
    const int pix0  = blockIdx.x * BLK;
    const int pix   = pix0 + tid;                 // window id in plane
    const bool live = (pix < NPIX);
    const int ho = pix / WO;
    const int wo = pix - ho * WO;
    const int c  = plane & (C - 1);               // C = 64, power of 2

    const float* xp = x + (size_t)plane * (H * W);

    float v[KK];
    int   id[KK];
    const int iy0 = 2 * ho - 1;
    const int ix0 = 2 * wo - 1;
#pragma unroll
    for (int dy = 0; dy < 3; ++dy) {
        const int  iy  = iy0 + dy;
        const bool yok = live && ((unsigned)iy < (unsigned)H);
#pragma unroll
        for (int dx = 0; dx < 3; ++dx) {
            const int  ix = ix0 + dx;
            const int  k  = dy * 3 + dx;
            const bool ok = yok && ((unsigned)ix < (unsigned)W);
            v[k]  = ok ? xp[iy * W + ix] : 0.0f;
            id[k] = k;
        }
    }

    // Compare-exchange: position a keeps the element that comes FIRST in the
    // stable descending order (greater value; exact tie -> smaller index).
    // Strict total order == jnp's stable argsort(-patches) result.
    auto CE = [&](int a, int b) {
        const float va = v[a],  vb = v[b];
        const int   ia = id[a], ib = id[b];
        const bool sw = (va < vb) || ((va == vb) && (ia > ib));
        v[a]  = sw ? vb : va;  v[b]  = sw ? va : vb;
        id[a] = sw ? ib : ia;  id[b] = sw ? ia : ib;
    };

    // Batcher odd-even mergesort on 0..7 (19 CEs) + insertion of 8 (8 CEs).
    CE(0,1); CE(2,3); CE(4,5); CE(6,7);
    CE(0,2); CE(1,3); CE(4,6); CE(5,7);
    CE(1,2); CE(5,6);
    CE(0,4); CE(1,5); CE(2,6); CE(3,7);
    CE(2,4); CE(3,5);
    CE(1,2); CE(3,4); CE(5,6);
    CE(7,8); CE(6,7); CE(5,6); CE(4,5); CE(3,4); CE(2,3); CE(1,2); CE(0,1);

    // Weighted sum with per-channel rank weights (block-uniform c -> s_loads).
    const float* sc = s + c * KK;
    float acc = 0.0f;
#pragma unroll
    for (int k = 0; k < KK; ++k) acc = fmaf(v[k], sc[k], acc);

    if (live) out[(size_t)plane * NPIX + pix] = acc;

    // Stage ranks in LDS: lorder[tid*9 + k]. Stride 9 floats across lanes ->
    // 2-way bank aliasing only (free on gfx950).
#pragma unroll
    for (int k = 0; k < KK; ++k) lorder[tid * KK + k] = (float)id[k];
    __syncthreads();

    // Coalesced float4 writeback of the block's contiguous order chunk.
    // Base float index = (plane*NPIX + pix0)*9 : divisible by 4 (2304/blk,
    // 28224/plane), so float4-aligned.
    const int nwin = min(BLK, NPIX - pix0);       // 256, or 64 for last block
    const int nf4  = (nwin * KK) >> 2;            // 576 or 144
    float4* __restrict__ ob =
        (float4*)(order + ((size_t)plane * NPIX + pix0) * KK);
    const float4* __restrict__ lb = (const float4*)lorder;
    for (int i = tid; i < nf4; i += BLK) ob[i] = lb[i];
}

extern "C" void kernel_launch(void* const* d_in, const int* in_sizes, int n_in,
                              void* d_out, int out_size, void* d_ws, size_t ws_size,
                              hipStream_t stream) {
    const float* x = (const float*)d_in[0];
    const float* s = (const float*)d_in[1];
    float* out   = (float*)d_out;
    float* order = out + (size_t)B * C * NPIX;    // second output, flat after first

    dim3 grid((NPIX + BLK - 1) / BLK, B * C);     // (13, 2048)
    rrsvm_kernel<<<grid, dim3(BLK), 0, stream>>>(x, s, out, order);
}

// Round 3
// 323.685 us; speedup vs baseline: 1.1354x; 1.0133x over previous
//
#include <hip/hip_runtime.h>

// RRSVM rank-weighted pooling, 3x3 / stride 2 / pad 1.
// x: [B=32, C=64, H=112, W=112] fp32;  s: [C, 3, 3] fp32
// out0: [B,C,56,56] fp32 ; out1: order [B,C,56,56,9] written as fp32.
//
// R3: block = (plane, 4 window-rows). Input rows staged in LDS via dense
// float4 loads (kills the 9 predicated stride-2 gathers per thread of R2).
// Order writes still staged in LDS -> coalesced float4 writeback.

constexpr int B  = 32;
constexpr int C  = 64;
constexpr int H  = 112;
constexpr int W  = 112;
constexpr int HO = 56;
constexpr int WO = 56;
constexpr int KK = 9;
constexpr int NPIX = HO * WO;          // 3136 windows per (b,c) plane
constexpr int BLK  = 256;
constexpr int LROW = 128;              // LDS row stride (floats)
constexpr int RPT  = 4;                // window-rows per block
constexpr int IR   = 2 * RPT + 1;      // input rows staged = 9

__global__ __launch_bounds__(BLK) void rrsvm_kernel(
    const float* __restrict__ x, const float* __restrict__ s,
    float* __restrict__ out, float* __restrict__ order)
{
    __shared__ float lx[IR * LROW];            // 9*128*4 = 4608 B
    __shared__ float lorder[RPT * WO * KK];    // 224*9*4 = 8064 B

    const int plane = blockIdx.y;              // b*C + c (block-uniform)
    const int ho0   = blockIdx.x;              // tile of 4 window-rows
    const int tid   = threadIdx.x;
    const int w     = tid >> 6;                // wave id 0..3 -> window-row
    const int lane  = tid & 63;                // lane -> window-col (56 live)
    const int c     = plane & (C - 1);

    const float* xp = x + (size_t)plane * (H * W);

    // ---- Stage 9 input rows (global rows 8*ho0-1 .. 8*ho0+7), cols 0..111,
    // shifted +1 in LDS so logical col -1 lands on the zeroed entry 0.
    // 9 rows * 28 float4 = 252 tasks, one per thread.
    if (tid < IR * (W / 4)) {                  // 252
        const int r = tid / (W / 4);           // 0..8
        const int cc = tid - r * (W / 4);      // 0..27
        const int grow = 8 * ho0 - 1 + r;      // -1..111
        float4 val = make_float4(0.f, 0.f, 0.f, 0.f);
        if ((unsigned)grow < (unsigned)H)      // only ho0==0, r==0 is OOB
            val = *(const float4*)(xp + grow * W + 4 * cc);
        float* dst = &lx[r * LROW + 1 + 4 * cc];
        dst[0] = val.x; dst[1] = val.y; dst[2] = val.z; dst[3] = val.w;
    }
    if (tid < IR) lx[tid * LROW] = 0.0f;       // logical col -1 = pad zero
    __syncthreads();

    // ---- Gather window from LDS. Window (ho,wo): rows 2w+dy, cols 2*wo-1+dx
    // -> LDS idx (2w+dy)*LROW + (2*wo+dx)  (the +1 shift handles col -1;
    //    max idx = 2*55+2 = 112 <= 112, in-row).
    const bool live = (lane < WO);
    const int  lc   = live ? lane : 0;         // keep dead lanes in-bounds
    const int  ho   = ho0 * RPT + w;

    float v[KK];
    int   id[KK];
#pragma unroll
    for (int dy = 0; dy < 3; ++dy)
#pragma unroll
        for (int dx = 0; dx < 3; ++dx) {
            const int k = dy * 3 + dx;
            v[k]  = lx[(2 * w + dy) * LROW + 2 * lc + dx];
            id[k] = k;
        }

    // ---- Sort descending by value; exact tie -> smaller index first.
    // Strict total order == jnp's stable argsort(-patches).
    auto CE = [&](int a, int b) {
        const float va = v[a],  vb = v[b];
        const int   ia = id[a], ib = id[b];
        const bool sw = (va < vb) || ((va == vb) && (ia > ib));
        v[a]  = sw ? vb : va;  v[b]  = sw ? va : vb;
        id[a] = sw ? ib : ia;  id[b] = sw ? ia : ib;
    };
    // Batcher odd-even mergesort on 0..7 (19 CEs) + insertion of 8 (8 CEs).
    CE(0,1); CE(2,3); CE(4,5); CE(6,7);
    CE(0,2); CE(1,3); CE(4,6); CE(5,7);
    CE(1,2); CE(5,6);
    CE(0,4); CE(1,5); CE(2,6); CE(3,7);
    CE(2,4); CE(3,5);
    CE(1,2); CE(3,4); CE(5,6);
    CE(7,8); CE(6,7); CE(5,6); CE(4,5); CE(3,4); CE(2,3); CE(1,2); CE(0,1);

    // ---- Weighted sum with per-channel rank weights (block-uniform c).
    const float* sc = s + c * KK;
    float acc = 0.0f;
#pragma unroll
    for (int k = 0; k < KK; ++k) acc = fmaf(v[k], sc[k], acc);

    if (live) {
        out[(size_t)plane * NPIX + ho * WO + lane] = acc;
        const int widx = w * WO + lane;        // window within tile, 0..223
#pragma unroll
        for (int k = 0; k < KK; ++k)
            lorder[widx * KK + k] = (float)id[k];   // stride 9 -> 2-way, free
    }
    __syncthreads();

    // ---- Coalesced float4 writeback of the tile's contiguous order chunk.
    // Base float idx = (plane*3136 + ho0*224)*9 : divisible by 4.
    float4* __restrict__ ob =
        (float4*)(order + ((size_t)plane * NPIX + (size_t)ho0 * RPT * WO) * KK);
    const float4* __restrict__ lb = (const float4*)lorder;
#pragma unroll
    for (int i = tid; i < RPT * WO * KK / 4; i += BLK)  // 504 float4
        ob[i] = lb[i];
}

extern "C" void kernel_launch(void* const* d_in, const int* in_sizes, int n_in,
                              void* d_out, int out_size, void* d_ws, size_t ws_size,
                              hipStream_t stream) {
    const float* x = (const float*)d_in[0];
    const float* s = (const float*)d_in[1];
    float* out   = (float*)d_out;
    float* order = out + (size_t)B * C * NPIX;   // second output, flat after first

    dim3 grid(HO / RPT, B * C);                  // (14, 2048)
    rrsvm_kernel<<<grid, dim3(BLK), 0, stream>>>(x, s, out, order);
}

// Round 5
// 314.139 us; speedup vs baseline: 1.1699x; 1.0304x over previous
//
#include <hip/hip_runtime.h>

// RRSVM rank-weighted pooling, 3x3 / stride 2 / pad 1.
// x: [B=32, C=64, H=112, W=112] fp32;  s: [C, 3, 3] fp32
// out0: [B,C,56,56] fp32 ; out1: order [B,C,56,56,9] written as fp32.
//
// R5 (= R4 fixed): nontemporal stores on both outputs (257 MB pure write
// stream; keep L2 for input rows). Uses a native clang ext_vector float4 —
// __builtin_nontemporal_store rejects HIP_vector_type<float,4>.
// Model: ~240us of dur is harness overhead (1GB ws poison fill + out
// poison + input restore); kernel itself ~84us vs ~58us traffic floor.

typedef float nfloat4 __attribute__((ext_vector_type(4)));

constexpr int B  = 32;
constexpr int C  = 64;
constexpr int H  = 112;
constexpr int W  = 112;
constexpr int HO = 56;
constexpr int WO = 56;
constexpr int KK = 9;
constexpr int NPIX = HO * WO;          // 3136 windows per (b,c) plane
constexpr int BLK  = 256;
constexpr int LROW = 128;              // LDS row stride (floats)
constexpr int RPT  = 4;                // window-rows per block
constexpr int IR   = 2 * RPT + 1;      // input rows staged = 9

__global__ __launch_bounds__(BLK) void rrsvm_kernel(
    const float* __restrict__ x, const float* __restrict__ s,
    float* __restrict__ out, float* __restrict__ order)
{
    __shared__ float lx[IR * LROW];            // 4608 B
    __shared__ float lorder[RPT * WO * KK];    // 8064 B

    const int plane = blockIdx.y;              // b*C + c (block-uniform)
    const int ho0   = blockIdx.x;              // tile of 4 window-rows
    const int tid   = threadIdx.x;
    const int w     = tid >> 6;                // wave id 0..3 -> window-row
    const int lane  = tid & 63;                // lane -> window-col (56 live)
    const int c     = plane & (C - 1);

    const float* xp = x + (size_t)plane * (H * W);

    // ---- Stage 9 input rows (global rows 8*ho0-1 .. 8*ho0+7), shifted +1
    // in LDS so logical col -1 lands on the zeroed entry 0.
    if (tid < IR * (W / 4)) {                  // 252 float4 tasks
        const int r  = tid / (W / 4);          // 0..8
        const int cc = tid - r * (W / 4);      // 0..27
        const int grow = 8 * ho0 - 1 + r;      // -1..111
        nfloat4 val = (nfloat4)0.0f;
        if ((unsigned)grow < (unsigned)H)      // only ho0==0, r==0 is OOB
            val = *(const nfloat4*)(xp + grow * W + 4 * cc);
        float* dst = &lx[r * LROW + 1 + 4 * cc];
        dst[0] = val.x; dst[1] = val.y; dst[2] = val.z; dst[3] = val.w;
    }
    if (tid < IR) lx[tid * LROW] = 0.0f;       // logical col -1 = pad zero
    __syncthreads();

    // ---- Gather window from LDS.
    const bool live = (lane < WO);
    const int  lc   = live ? lane : 0;
    const int  ho   = ho0 * RPT + w;

    float v[KK];
    float fid[KK];
#pragma unroll
    for (int dy = 0; dy < 3; ++dy)
#pragma unroll
        for (int dx = 0; dx < 3; ++dx) {
            const int k = dy * 3 + dx;
            v[k]   = lx[(2 * w + dy) * LROW + 2 * lc + dx];
            fid[k] = (float)k;                 // compile-time constant
        }

    // ---- Sort descending by value; exact tie -> smaller index first.
    // (ids as floats: comparison exact for 0..8.)
    auto CE = [&](int a, int b) {
        const float va = v[a],   vb = v[b];
        const float fa = fid[a], fb = fid[b];
        const bool sw = (va < vb) || ((va == vb) && (fa > fb));
        v[a]   = sw ? vb : va;  v[b]   = sw ? va : vb;
        fid[a] = sw ? fb : fa;  fid[b] = sw ? fa : fb;
    };
    // Batcher odd-even mergesort on 0..7 (19 CEs) + insertion of 8 (8 CEs).
    CE(0,1); CE(2,3); CE(4,5); CE(6,7);
    CE(0,2); CE(1,3); CE(4,6); CE(5,7);
    CE(1,2); CE(5,6);
    CE(0,4); CE(1,5); CE(2,6); CE(3,7);
    CE(2,4); CE(3,5);
    CE(1,2); CE(3,4); CE(5,6);
    CE(7,8); CE(6,7); CE(5,6); CE(4,5); CE(3,4); CE(2,3); CE(1,2); CE(0,1);

    // ---- Weighted sum with per-channel rank weights (block-uniform c).
    const float* sc = s + c * KK;
    float acc = 0.0f;
#pragma unroll
    for (int k = 0; k < KK; ++k) acc = fmaf(v[k], sc[k], acc);

    if (live) {
        __builtin_nontemporal_store(acc, out + (size_t)plane * NPIX + ho * WO + lane);
        const int widx = w * WO + lane;        // window within tile, 0..223
#pragma unroll
        for (int k = 0; k < KK; ++k)
            lorder[widx * KK + k] = fid[k];    // stride 9 -> 2-way, free
    }
    __syncthreads();

    // ---- Coalesced nontemporal float4 writeback of the tile's order chunk.
    nfloat4* __restrict__ ob =
        (nfloat4*)(order + ((size_t)plane * NPIX + (size_t)ho0 * RPT * WO) * KK);
    const nfloat4* __restrict__ lb = (const nfloat4*)lorder;
#pragma unroll
    for (int i = tid; i < RPT * WO * KK / 4; i += BLK)  // 504 float4
        __builtin_nontemporal_store(lb[i], ob + i);
}

extern "C" void kernel_launch(void* const* d_in, const int* in_sizes, int n_in,
                              void* d_out, int out_size, void* d_ws, size_t ws_size,
                              hipStream_t stream) {
    const float* x = (const float*)d_in[0];
    const float* s = (const float*)d_in[1];
    float* out   = (float*)d_out;
    float* order = out + (size_t)B * C * NPIX;   // second output, flat after first

    dim3 grid(HO / RPT, B * C);                  // (14, 2048)
    rrsvm_kernel<<<grid, dim3(BLK), 0, stream>>>(x, s, out, order);
}